// Round 1
// baseline (518.401 us; speedup 1.0000x reference)
//
#include <hip/hip_runtime.h>

#define EDGES        800000
#define IN_F         64
#define HID          128
#define TPB          256          // 4 waves per WG
#define EDGES_PER_WG 128          // 32 edges per wave (two 16-row strips)
#define NWG          (EDGES / EDGES_PER_WG)   // 6250

typedef _Float16 half8 __attribute__((ext_vector_type(8)));
typedef float    f32x4 __attribute__((ext_vector_type(4)));

// f16 copies of the weights, produced by a prologue kernel each call.
// (Device globals: not poisoned by the harness, rewritten every call.)
__device__ __align__(16) _Float16 g_w1[HID * IN_F];   // [128][64]  row-major (out, in)
__device__ __align__(16) _Float16 g_w2[HID * HID];    // [128][128]
__device__ __align__(16) _Float16 g_w3[HID * HID];    // [128][128]

__global__ void cvt_weights(const float* __restrict__ W1,
                            const float* __restrict__ W2,
                            const float* __restrict__ W3) {
    int i = blockIdx.x * TPB + threadIdx.x;            // grid 64*256 = 16384
    if (i < HID * IN_F) g_w1[i] = (_Float16)W1[i];     // RTN cvt
    g_w2[i] = (_Float16)W2[i];
    g_w3[i] = (_Float16)W3[i];
}

// tanh(x) = 1 - 2/(e^{2x}+1): 3 VALU + 2 transcendental. Preactivations are
// bounded (|x| <~ 10) so exp2 cannot overflow (needs x > 44).
__device__ __forceinline__ float fast_tanh(float x) {
    float e = __builtin_amdgcn_exp2f(2.8853900817779268f * x);   // e^{2x}
    return 1.0f - 2.0f * __builtin_amdgcn_rcpf(e + 1.0f);
}

__device__ __forceinline__ float fast_sigmoid(float x) {
    return __builtin_amdgcn_rcpf(1.0f + __builtin_amdgcn_exp2f(-1.4426950408889634f * x));
}

__global__ __launch_bounds__(TPB, 4)
void mlp_fused(const float* __restrict__ ea,
               const float* __restrict__ b1,
               const float* __restrict__ b2,
               const float* __restrict__ b3,
               const float* __restrict__ w4,
               const float* __restrict__ b4,
               float* __restrict__ out) {
    // Wave-private H tile: 32 edges x 128 hidden, f16, +8 pad (row = 272B,
    // 16B-aligned for ds_read_b128; 68 dwords stride -> 2-way bank alias = free).
    __shared__ _Float16 H[4][32][136];

    const int tid  = threadIdx.x;
    const int w    = tid >> 6;          // wave 0..3
    const int lane = tid & 63;
    const int l16  = lane & 15;
    const int quad = lane >> 4;         // 0..3
    const int ebase = blockIdx.x * EDGES_PER_WG + w * 32;

    // ---------------- Layer 1: A[32x64](f32->f16) @ W1[n][k] ----------------
    // A-frag (16x16x32): lane holds A[m=l16][k = 32*s + 8*quad + j], j=0..7
    half8 a0[2], a1v[2];                // strip0 (rows 0-15), strip1 (rows 16-31)
    #pragma unroll
    for (int s = 0; s < 2; ++s) {
        const float* r0 = ea + (long)(ebase + l16) * IN_F + s * 32 + quad * 8;
        const float* r1 = r0 + 16 * IN_F;
        float4 x0 = ((const float4*)r0)[0], x1 = ((const float4*)r0)[1];
        float4 y0 = ((const float4*)r1)[0], y1 = ((const float4*)r1)[1];
        half8 h0, h1;
        h0[0]=(_Float16)x0.x; h0[1]=(_Float16)x0.y; h0[2]=(_Float16)x0.z; h0[3]=(_Float16)x0.w;
        h0[4]=(_Float16)x1.x; h0[5]=(_Float16)x1.y; h0[6]=(_Float16)x1.z; h0[7]=(_Float16)x1.w;
        h1[0]=(_Float16)y0.x; h1[1]=(_Float16)y0.y; h1[2]=(_Float16)y0.z; h1[3]=(_Float16)y0.w;
        h1[4]=(_Float16)y1.x; h1[5]=(_Float16)y1.y; h1[6]=(_Float16)y1.z; h1[7]=(_Float16)y1.w;
        a0[s] = h0; a1v[s] = h1;
    }
    #pragma unroll
    for (int nbp = 0; nbp < 4; ++nbp) {
        const int n0 = l16 + 16 * (2 * nbp);
        const int n1 = l16 + 16 * (2 * nbp + 1);
        f32x4 acc00, acc01, acc10, acc11;            // (strip, nb)
        const float bv0 = b1[n0], bv1 = b1[n1];
        #pragma unroll
        for (int r = 0; r < 4; ++r) { acc00[r]=bv0; acc01[r]=bv0; acc10[r]=bv1; acc11[r]=bv1; }
        #pragma unroll
        for (int s = 0; s < 2; ++s) {
            half8 bf0 = *(const half8*)(g_w1 + n0 * IN_F + s * 32 + quad * 8);
            half8 bf1 = *(const half8*)(g_w1 + n1 * IN_F + s * 32 + quad * 8);
            acc00 = __builtin_amdgcn_mfma_f32_16x16x32_f16(a0[s],  bf0, acc00, 0, 0, 0);
            acc01 = __builtin_amdgcn_mfma_f32_16x16x32_f16(a1v[s], bf0, acc01, 0, 0, 0);
            acc10 = __builtin_amdgcn_mfma_f32_16x16x32_f16(a0[s],  bf1, acc10, 0, 0, 0);
            acc11 = __builtin_amdgcn_mfma_f32_16x16x32_f16(a1v[s], bf1, acc11, 0, 0, 0);
        }
        // C/D: lane holds D[m = quad*4 + r][n = l16(+16nb)]
        #pragma unroll
        for (int r = 0; r < 4; ++r) {
            const int m = quad * 4 + r;
            H[w][m][n0]      = (_Float16)fast_tanh(acc00[r]);
            H[w][m + 16][n0] = (_Float16)fast_tanh(acc01[r]);
            H[w][m][n1]      = (_Float16)fast_tanh(acc10[r]);
            H[w][m + 16][n1] = (_Float16)fast_tanh(acc11[r]);
        }
    }
    __syncthreads();

    // ---------------- Layer 2: H @ W2[n][k] ----------------
    half8 a20[4], a21[4];
    #pragma unroll
    for (int s = 0; s < 4; ++s) {
        a20[s] = *(const half8*)&H[w][l16][s * 32 + quad * 8];
        a21[s] = *(const half8*)&H[w][16 + l16][s * 32 + quad * 8];
    }
    #pragma unroll
    for (int nbp = 0; nbp < 4; ++nbp) {
        const int n0 = l16 + 16 * (2 * nbp);
        const int n1 = l16 + 16 * (2 * nbp + 1);
        f32x4 acc00, acc01, acc10, acc11;
        const float bv0 = b2[n0], bv1 = b2[n1];
        #pragma unroll
        for (int r = 0; r < 4; ++r) { acc00[r]=bv0; acc01[r]=bv0; acc10[r]=bv1; acc11[r]=bv1; }
        #pragma unroll
        for (int s = 0; s < 4; ++s) {
            half8 bf0 = *(const half8*)(g_w2 + n0 * HID + s * 32 + quad * 8);
            half8 bf1 = *(const half8*)(g_w2 + n1 * HID + s * 32 + quad * 8);
            acc00 = __builtin_amdgcn_mfma_f32_16x16x32_f16(a20[s], bf0, acc00, 0, 0, 0);
            acc01 = __builtin_amdgcn_mfma_f32_16x16x32_f16(a21[s], bf0, acc01, 0, 0, 0);
            acc10 = __builtin_amdgcn_mfma_f32_16x16x32_f16(a20[s], bf1, acc10, 0, 0, 0);
            acc11 = __builtin_amdgcn_mfma_f32_16x16x32_f16(a21[s], bf1, acc11, 0, 0, 0);
        }
        #pragma unroll
        for (int r = 0; r < 4; ++r) {
            const int m = quad * 4 + r;
            H[w][m][n0]      = (_Float16)fast_tanh(acc00[r]);
            H[w][m + 16][n0] = (_Float16)fast_tanh(acc01[r]);
            H[w][m][n1]      = (_Float16)fast_tanh(acc10[r]);
            H[w][m + 16][n1] = (_Float16)fast_tanh(acc11[r]);
        }
    }
    __syncthreads();

    // ---------------- Layer 3 (+ fused layer 4 dot) ----------------
    half8 a30[4], a31[4];
    #pragma unroll
    for (int s = 0; s < 4; ++s) {
        a30[s] = *(const half8*)&H[w][l16][s * 32 + quad * 8];
        a31[s] = *(const half8*)&H[w][16 + l16][s * 32 + quad * 8];
    }
    f32x4 p0, p1;                       // per-lane partial dot, strip0/strip1
    #pragma unroll
    for (int r = 0; r < 4; ++r) { p0[r] = 0.0f; p1[r] = 0.0f; }
    #pragma unroll
    for (int nbp = 0; nbp < 4; ++nbp) {
        const int n0 = l16 + 16 * (2 * nbp);
        const int n1 = l16 + 16 * (2 * nbp + 1);
        f32x4 acc00, acc01, acc10, acc11;
        const float bv0 = b3[n0], bv1 = b3[n1];
        #pragma unroll
        for (int r = 0; r < 4; ++r) { acc00[r]=bv0; acc01[r]=bv0; acc10[r]=bv1; acc11[r]=bv1; }
        #pragma unroll
        for (int s = 0; s < 4; ++s) {
            half8 bf0 = *(const half8*)(g_w3 + n0 * HID + s * 32 + quad * 8);
            half8 bf1 = *(const half8*)(g_w3 + n1 * HID + s * 32 + quad * 8);
            acc00 = __builtin_amdgcn_mfma_f32_16x16x32_f16(a30[s], bf0, acc00, 0, 0, 0);
            acc01 = __builtin_amdgcn_mfma_f32_16x16x32_f16(a31[s], bf0, acc01, 0, 0, 0);
            acc10 = __builtin_amdgcn_mfma_f32_16x16x32_f16(a30[s], bf1, acc10, 0, 0, 0);
            acc11 = __builtin_amdgcn_mfma_f32_16x16x32_f16(a31[s], bf1, acc11, 0, 0, 0);
        }
        const float wv0 = w4[n0], wv1 = w4[n1];      // W4 row, fp32 (precision)
        #pragma unroll
        for (int r = 0; r < 4; ++r) {
            p0[r] += fast_tanh(acc00[r]) * wv0 + fast_tanh(acc10[r]) * wv1;
            p1[r] += fast_tanh(acc01[r]) * wv0 + fast_tanh(acc11[r]) * wv1;
        }
    }
    // Reduce over n: sum across the 16 lanes sharing `quad` (masks 1..8 stay
    // inside each 16-lane group).
    #pragma unroll
    for (int mask = 1; mask <= 8; mask <<= 1) {
        #pragma unroll
        for (int r = 0; r < 4; ++r) {
            p0[r] += __shfl_xor(p0[r], mask, 64);
            p1[r] += __shfl_xor(p1[r], mask, 64);
        }
    }
    const float bb = b4[0];
    if (l16 < 8) {                       // 8 lanes per quad write 8 edges
        const int r = l16 & 3;
        f32x4 ps = (l16 < 4) ? p0 : p1;
        float v = ps[0];
        v = (r == 1) ? ps[1] : v;
        v = (r == 2) ? ps[2] : v;
        v = (r == 3) ? ps[3] : v;
        const int m = quad * 4 + r + 16 * (l16 >> 2);
        out[ebase + m] = fast_sigmoid(v + bb);
    }
}

extern "C" void kernel_launch(void* const* d_in, const int* in_sizes, int n_in,
                              void* d_out, int out_size, void* d_ws, size_t ws_size,
                              hipStream_t stream) {
    // setup_inputs order: x, edge_index, edge_attr, W1,b1, W2,b2, W3,b3, W4,b4
    const float* ea = (const float*)d_in[2];
    const float* W1 = (const float*)d_in[3];
    const float* b1 = (const float*)d_in[4];
    const float* W2 = (const float*)d_in[5];
    const float* b2 = (const float*)d_in[6];
    const float* W3 = (const float*)d_in[7];
    const float* b3 = (const float*)d_in[8];
    const float* W4 = (const float*)d_in[9];
    const float* b4 = (const float*)d_in[10];
    float* out = (float*)d_out;

    hipLaunchKernelGGL(cvt_weights, dim3((HID * HID) / TPB), dim3(TPB), 0, stream,
                       W1, W2, W3);
    hipLaunchKernelGGL(mlp_fused, dim3(NWG), dim3(TPB), 0, stream,
                       ea, b1, b2, b3, W4, b4, out);
}

// Round 3
// 501.111 us; speedup vs baseline: 1.0345x; 1.0345x over previous
//
#include <hip/hip_runtime.h>

#define EDGES        800000
#define IN_F         64
#define HID          128
#define TPB          256          // 4 waves per WG
#define EPW          32           // edges per wave (two 16-edge strips)
#define EDGES_PER_WG 128
#define NWG          (EDGES / EDGES_PER_WG)   // 6250
#define HSTR         136          // H row stride in halfs (+8 pad: conflict-free b64/b128)

typedef _Float16 half8  __attribute__((ext_vector_type(8)));
typedef _Float16 half4  __attribute__((ext_vector_type(4)));
typedef __fp16   fp16x2 __attribute__((ext_vector_type(2)));   // cvt_pkrtz return type
typedef float    f32x4  __attribute__((ext_vector_type(4)));

// f16 weights, rewritten by a prologue kernel every call.
__device__ __align__(16) _Float16 g_w1[HID * IN_F];   // [h'][k] row-major
__device__ __align__(16) _Float16 g_w2[HID * HID];
__device__ __align__(16) _Float16 g_w3[HID * HID];

__global__ void cvt_weights(const float* __restrict__ W1,
                            const float* __restrict__ W2,
                            const float* __restrict__ W3) {
    int i = blockIdx.x * TPB + threadIdx.x;            // grid 64*256 = 16384
    if (i < HID * IN_F) g_w1[i] = (_Float16)W1[i];
    g_w2[i] = (_Float16)W2[i];
    g_w3[i] = (_Float16)W3[i];
}

// tanh(x) = 1 - 2/(e^{2x}+1): 2 transcendental + 3 VALU. Preacts bounded
// (|x| < ~40), exp2 arg < 128 -> no overflow.
__device__ __forceinline__ float fast_tanh(float x) {
    float e = __builtin_amdgcn_exp2f(2.8853900817779268f * x);
    return 1.0f - 2.0f * __builtin_amdgcn_rcpf(e + 1.0f);
}
__device__ __forceinline__ float fast_sigmoid(float x) {
    return __builtin_amdgcn_rcpf(1.0f + __builtin_amdgcn_exp2f(-1.4426950408889634f * x));
}

// tanh + pack 4 f32 accs -> half4 (2x v_cvt_pkrtz_f16_f32 instead of 4 cvt + packs)
__device__ __forceinline__ half4 tanh_pack4(f32x4 a) {
    fp16x2 lo = __builtin_amdgcn_cvt_pkrtz(fast_tanh(a[0]), fast_tanh(a[1]));
    fp16x2 hi = __builtin_amdgcn_cvt_pkrtz(fast_tanh(a[2]), fast_tanh(a[3]));
    half4 r;
    r[0] = (_Float16)lo[0]; r[1] = (_Float16)lo[1];
    r[2] = (_Float16)hi[0]; r[3] = (_Float16)hi[1];
    return r;
}

// Orientation: every layer computed as D = W (A-operand) x Act (B-operand).
//   A-frag: lane holds W[i = l16 (+16*it)][k = q*8 + j]      (row-major, b128)
//   B-frag: lane holds Act[e = l16 (+16*strip)][k = q*8 + j] (edge-major, b128)
//   D:      lane holds O[h' = it*16 + q*4 + r][e = l16 (+16*strip)]
// -> per lane 4 CONTIGUOUS h' at fixed edge: packed ds_write_b64, and next
//    layer's B-frag is a natural edge-major ds_read_b128. H is wave-private,
//    LDS ops within a wave are ordered -> NO __syncthreads anywhere.
__global__ __launch_bounds__(TPB, 4)
void mlp_fused(const float* __restrict__ ea,
               const float* __restrict__ b1,
               const float* __restrict__ b2,
               const float* __restrict__ b3,
               const float* __restrict__ w4,
               const float* __restrict__ b4,
               float* __restrict__ out) {
    __shared__ _Float16 H[4][EPW][HSTR];   // 34816 B -> 4 WG/CU

    const int tid  = threadIdx.x;
    const int w    = tid >> 6;
    const int lane = tid & 63;
    const int l16  = lane & 15;
    const int q    = lane >> 4;            // 0..3
    const int ebase = blockIdx.x * EDGES_PER_WG + w * EPW;
    _Float16 (*Hw)[HSTR] = H[w];

    // ---------------- Layer 1: B-frags straight from global ----------------
    half8 bf1[2][2];                       // [strip][kstep]
    #pragma unroll
    for (int s = 0; s < 2; ++s) {
        #pragma unroll
        for (int t = 0; t < 2; ++t) {
            const float* p = ea + (long)(ebase + s * 16 + l16) * IN_F + t * 32 + q * 8;
            float4 x0 = ((const float4*)p)[0], x1 = ((const float4*)p)[1];
            half8 h;
            h[0]=(_Float16)x0.x; h[1]=(_Float16)x0.y; h[2]=(_Float16)x0.z; h[3]=(_Float16)x0.w;
            h[4]=(_Float16)x1.x; h[5]=(_Float16)x1.y; h[6]=(_Float16)x1.z; h[7]=(_Float16)x1.w;
            bf1[s][t] = h;
        }
    }
    #pragma unroll
    for (int it = 0; it < 8; ++it) {
        float4 bv = *(const float4*)(b1 + it * 16 + q * 4);
        f32x4 acc0, acc1;
        acc0[0]=bv.x; acc0[1]=bv.y; acc0[2]=bv.z; acc0[3]=bv.w;
        acc1 = acc0;
        #pragma unroll
        for (int t = 0; t < 2; ++t) {
            half8 af = *(const half8*)(g_w1 + (it * 16 + l16) * IN_F + t * 32 + q * 8);
            acc0 = __builtin_amdgcn_mfma_f32_16x16x32_f16(af, bf1[0][t], acc0, 0, 0, 0);
            acc1 = __builtin_amdgcn_mfma_f32_16x16x32_f16(af, bf1[1][t], acc1, 0, 0, 0);
        }
        *(half4*)&Hw[l16]     [it * 16 + q * 4] = tanh_pack4(acc0);
        *(half4*)&Hw[16 + l16][it * 16 + q * 4] = tanh_pack4(acc1);
    }

    // ---------------- Layer 2 ----------------
    half8 bf2[2][4];
    #pragma unroll
    for (int s = 0; s < 2; ++s)
        #pragma unroll
        for (int t = 0; t < 4; ++t)
            bf2[s][t] = *(const half8*)&Hw[s * 16 + l16][t * 32 + q * 8];
    #pragma unroll
    for (int it = 0; it < 8; ++it) {
        float4 bv = *(const float4*)(b2 + it * 16 + q * 4);
        f32x4 acc0, acc1;
        acc0[0]=bv.x; acc0[1]=bv.y; acc0[2]=bv.z; acc0[3]=bv.w;
        acc1 = acc0;
        #pragma unroll
        for (int t = 0; t < 4; ++t) {
            half8 af = *(const half8*)(g_w2 + (it * 16 + l16) * HID + t * 32 + q * 8);
            acc0 = __builtin_amdgcn_mfma_f32_16x16x32_f16(af, bf2[0][t], acc0, 0, 0, 0);
            acc1 = __builtin_amdgcn_mfma_f32_16x16x32_f16(af, bf2[1][t], acc1, 0, 0, 0);
        }
        *(half4*)&Hw[l16]     [it * 16 + q * 4] = tanh_pack4(acc0);
        *(half4*)&Hw[16 + l16][it * 16 + q * 4] = tanh_pack4(acc1);
    }

    // ---------------- Layer 3 + fused layer-4 dot ----------------
    half8 bf3[2][4];
    #pragma unroll
    for (int s = 0; s < 2; ++s)
        #pragma unroll
        for (int t = 0; t < 4; ++t)
            bf3[s][t] = *(const half8*)&Hw[s * 16 + l16][t * 32 + q * 8];
    float p0 = 0.0f, p1 = 0.0f;
    #pragma unroll
    for (int it = 0; it < 8; ++it) {
        float4 bv = *(const float4*)(b3 + it * 16 + q * 4);
        float4 wv = *(const float4*)(w4 + it * 16 + q * 4);
        f32x4 acc0, acc1;
        acc0[0]=bv.x; acc0[1]=bv.y; acc0[2]=bv.z; acc0[3]=bv.w;
        acc1 = acc0;
        #pragma unroll
        for (int t = 0; t < 4; ++t) {
            half8 af = *(const half8*)(g_w3 + (it * 16 + l16) * HID + t * 32 + q * 8);
            acc0 = __builtin_amdgcn_mfma_f32_16x16x32_f16(af, bf3[0][t], acc0, 0, 0, 0);
            acc1 = __builtin_amdgcn_mfma_f32_16x16x32_f16(af, bf3[1][t], acc1, 0, 0, 0);
        }
        p0 += fast_tanh(acc0[0]) * wv.x + fast_tanh(acc0[1]) * wv.y
            + fast_tanh(acc0[2]) * wv.z + fast_tanh(acc0[3]) * wv.w;
        p1 += fast_tanh(acc1[0]) * wv.x + fast_tanh(acc1[1]) * wv.y
            + fast_tanh(acc1[2]) * wv.z + fast_tanh(acc1[3]) * wv.w;
    }
    // Sum over hidden: partials live in the 4 lanes sharing l16 (q = 0..3).
    p0 += __shfl_xor(p0, 16, 64);  p0 += __shfl_xor(p0, 32, 64);
    p1 += __shfl_xor(p1, 16, 64);  p1 += __shfl_xor(p1, 32, 64);
    const float bb = b4[0];
    if (lane < 16)      out[ebase + lane] = fast_sigmoid(p0 + bb);
    else if (lane < 32) out[ebase + lane] = fast_sigmoid(p1 + bb);  // strip-1 edges 16..31
}

extern "C" void kernel_launch(void* const* d_in, const int* in_sizes, int n_in,
                              void* d_out, int out_size, void* d_ws, size_t ws_size,
                              hipStream_t stream) {
    // setup_inputs order: x, edge_index, edge_attr, W1,b1, W2,b2, W3,b3, W4,b4
    const float* ea = (const float*)d_in[2];
    const float* W1 = (const float*)d_in[3];
    const float* b1 = (const float*)d_in[4];
    const float* W2 = (const float*)d_in[5];
    const float* b2 = (const float*)d_in[6];
    const float* W3 = (const float*)d_in[7];
    const float* b3 = (const float*)d_in[8];
    const float* W4 = (const float*)d_in[9];
    const float* b4 = (const float*)d_in[10];
    float* out = (float*)d_out;

    hipLaunchKernelGGL(cvt_weights, dim3((HID * HID) / TPB), dim3(TPB), 0, stream,
                       W1, W2, W3);
    hipLaunchKernelGGL(mlp_fused, dim3(NWG), dim3(TPB), 0, stream,
                       ea, b1, b2, b3, W4, b4, out);
}